// Round 1
// baseline (52726.678 us; speedup 1.0000x reference)
//
#include <hip/hip_runtime.h>

// Problem constants (B,S,F,L) = (512, 1024, 64, 128)
constexpr int Bn = 512;
constexpr int Sn = 1024;
constexpr int Fn = 64;
constexpr int Ln = 128;
constexpr int Gn = 4 * Ln;  // 512 gates (i,f,g,o)

__device__ __forceinline__ float fast_rcp(float v) { return __builtin_amdgcn_rcpf(v); }
__device__ __forceinline__ float fsigmoid(float v) { return fast_rcp(1.0f + __expf(-v)); }
__device__ __forceinline__ float ftanh(float v) { return 1.0f - 2.0f * fast_rcp(1.0f + __expf(2.0f * v)); }

// Fold decoder dense layer into the decoder recurrence:
//   W_comb[t,l] = W_hh_dec[t,l] + sum_j W_ih_dec[t,j] * W_dense[j,l]
//   b_comb[t]   = b_ih_dec[t] + b_hh_dec[t] + sum_j W_ih_dec[t,j] * b_dense[j]
__global__ void combine_dec_kernel(const float* __restrict__ Wih, const float* __restrict__ Whh,
                                   const float* __restrict__ bih, const float* __restrict__ bhh,
                                   const float* __restrict__ Wd, const float* __restrict__ bd,
                                   float* __restrict__ Wc, float* __restrict__ bc) {
  const int t = blockIdx.x;   // gate row 0..511
  const int l = threadIdx.x;  // latent col 0..127
  float s = Whh[t * Ln + l];
#pragma unroll
  for (int j = 0; j < Fn; ++j) s += Wih[t * Fn + j] * Wd[j * Ln + l];
  Wc[t * Ln + l] = s;
  if (l == 0) {
    float sb = bih[t] + bhh[t];
#pragma unroll
    for (int j = 0; j < Fn; ++j) sb += Wih[t * Fn + j] * bd[j];
    bc[t] = sb;
  }
}

// Persistent RNN kernel: 256 blocks x 512 threads; block handles 2 batch
// elements end-to-end (1024 enc steps + 1024 dec steps). Thread t owns gate
// row t; weights live in VGPRs; h exchanged via LDS (broadcast reads).
__global__ __launch_bounds__(512, 2) void rae_persistent_kernel(
    const float* __restrict__ x,
    const float* __restrict__ Wih_e, const float* __restrict__ Whh_e,
    const float* __restrict__ bih_e, const float* __restrict__ bhh_e,
    const float* __restrict__ Wc, const float* __restrict__ bc,
    const float* __restrict__ Wd, const float* __restrict__ bd,
    float* __restrict__ out) {
  const int t = threadIdx.x;      // gate id 0..511
  const int b0 = blockIdx.x * 2;  // two batch elements per block

  __shared__ __align__(16) float2 hp[Ln];  // (h[b0][l], h[b0+1][l]) interleaved
  __shared__ __align__(16) float2 gp[Gn];  // activated gates, both elems

  // ---- encoder weights into registers ----
  float wh[Ln];  // reused for W_comb in decoder phase
  float wx[Fn];
  {
    const float4* p = (const float4*)(Wih_e + t * Fn);
#pragma unroll
    for (int k = 0; k < Fn / 4; ++k) {
      float4 v = p[k];
      wx[4 * k] = v.x; wx[4 * k + 1] = v.y; wx[4 * k + 2] = v.z; wx[4 * k + 3] = v.w;
    }
  }
  {
    const float4* p = (const float4*)(Whh_e + t * Ln);
#pragma unroll
    for (int k = 0; k < Ln / 4; ++k) {
      float4 v = p[k];
      wh[4 * k] = v.x; wh[4 * k + 1] = v.y; wh[4 * k + 2] = v.z; wh[4 * k + 3] = v.w;
    }
  }
  float bias = bih_e[t] + bhh_e[t];

  float c0 = 0.0f, c1 = 0.0f;
  if (t < Ln) hp[t] = make_float2(0.0f, 0.0f);
  __syncthreads();

  const float* xp0 = x + (size_t)b0 * Sn * Fn;
  const float* xp1 = xp0 + (size_t)Sn * Fn;
  const bool is_g = ((t >> 7) == 2);  // gate rows 256..383 use tanh; wave-uniform

  // ================= encoder: 1024 steps =================
  for (int step = 0; step < Sn; ++step) {
    float acc0 = bias, acc1 = bias;
    // x contribution: block-uniform addresses -> scalar loads (SGPR operands)
    const float4* xv0 = (const float4*)(xp0 + step * Fn);
    const float4* xv1 = (const float4*)(xp1 + step * Fn);
#pragma unroll
    for (int k = 0; k < Fn / 4; ++k) {
      float4 a = xv0[k];
      float4 b = xv1[k];
      acc0 += wx[4 * k] * a.x + wx[4 * k + 1] * a.y + wx[4 * k + 2] * a.z + wx[4 * k + 3] * a.w;
      acc1 += wx[4 * k] * b.x + wx[4 * k + 1] * b.y + wx[4 * k + 2] * b.z + wx[4 * k + 3] * b.w;
    }
    // h contribution: LDS broadcast float4 reads = 2 latents x 2 elems each
    const float4* h4 = (const float4*)hp;
#pragma unroll
    for (int k = 0; k < Ln / 2; ++k) {
      float4 hv = h4[k];
      acc0 += wh[2 * k] * hv.x + wh[2 * k + 1] * hv.z;
      acc1 += wh[2 * k] * hv.y + wh[2 * k + 1] * hv.w;
    }
    float a0 = is_g ? ftanh(acc0) : fsigmoid(acc0);
    float a1 = is_g ? ftanh(acc1) : fsigmoid(acc1);
    gp[t] = make_float2(a0, a1);
    __syncthreads();
    if (t < Ln) {
      float2 gi = gp[t], gf = gp[Ln + t], gg = gp[2 * Ln + t], go = gp[3 * Ln + t];
      c0 = gf.x * c0 + gi.x * gg.x;
      c1 = gf.y * c1 + gi.y * gg.y;
      hp[t] = make_float2(go.x * ftanh(c0), go.y * ftanh(c1));
    }
    __syncthreads();
  }

  // ================= decoder: 1024 steps =================
  {
    const float4* p = (const float4*)(Wc + t * Ln);
#pragma unroll
    for (int k = 0; k < Ln / 4; ++k) {
      float4 v = p[k];
      wh[4 * k] = v.x; wh[4 * k + 1] = v.y; wh[4 * k + 2] = v.z; wh[4 * k + 3] = v.w;
    }
  }
  bias = bc[t];
  // dense epilogue slice: output j = t>>3, k-slice = (t&7)*16
  const int oj = t >> 3;
  const int ks = (t & 7) * 16;
  float dw[16];
  {
    const float4* p = (const float4*)(Wd + oj * Ln + ks);
#pragma unroll
    for (int k = 0; k < 4; ++k) {
      float4 v = p[k];
      dw[4 * k] = v.x; dw[4 * k + 1] = v.y; dw[4 * k + 2] = v.z; dw[4 * k + 3] = v.w;
    }
  }
  const float dbias = bd[oj];
  float* op0 = out + (size_t)b0 * Sn * Fn;
  float* op1 = op0 + (size_t)Sn * Fn;

  for (int step = 0; step < Sn; ++step) {
    float acc0 = bias, acc1 = bias;
    const float4* h4 = (const float4*)hp;
#pragma unroll
    for (int k = 0; k < Ln / 2; ++k) {
      float4 hv = h4[k];
      acc0 += wh[2 * k] * hv.x + wh[2 * k + 1] * hv.z;
      acc1 += wh[2 * k] * hv.y + wh[2 * k + 1] * hv.w;
    }
    float a0 = is_g ? ftanh(acc0) : fsigmoid(acc0);
    float a1 = is_g ? ftanh(acc1) : fsigmoid(acc1);
    gp[t] = make_float2(a0, a1);
    __syncthreads();
    if (t < Ln) {
      float2 gi = gp[t], gf = gp[Ln + t], gg = gp[2 * Ln + t], go = gp[3 * Ln + t];
      c0 = gf.x * c0 + gi.x * gg.x;
      c1 = gf.y * c1 + gi.y * gg.y;
      hp[t] = make_float2(go.x * ftanh(c0), go.y * ftanh(c1));
    }
    __syncthreads();
    // dense epilogue: out[b, S-1-step, :] = W_dense @ h + b_dense
    float d0 = 0.0f, d1 = 0.0f;
#pragma unroll
    for (int k = 0; k < 8; ++k) {
      float4 hv = h4[ks / 2 + k];
      d0 += dw[2 * k] * hv.x + dw[2 * k + 1] * hv.z;
      d1 += dw[2 * k] * hv.y + dw[2 * k + 1] * hv.w;
    }
    d0 += __shfl_xor(d0, 1); d1 += __shfl_xor(d1, 1);
    d0 += __shfl_xor(d0, 2); d1 += __shfl_xor(d1, 2);
    d0 += __shfl_xor(d0, 4); d1 += __shfl_xor(d1, 4);
    if ((t & 7) == 0) {
      const int row = Sn - 1 - step;
      op0[row * Fn + oj] = d0 + dbias;
      op1[row * Fn + oj] = d1 + dbias;
    }
  }
}

extern "C" void kernel_launch(void* const* d_in, const int* in_sizes, int n_in,
                              void* d_out, int out_size, void* d_ws, size_t ws_size,
                              hipStream_t stream) {
  const float* x     = (const float*)d_in[0];
  const float* Wih_e = (const float*)d_in[1];
  const float* Whh_e = (const float*)d_in[2];
  const float* bih_e = (const float*)d_in[3];
  const float* bhh_e = (const float*)d_in[4];
  const float* Wih_d = (const float*)d_in[5];
  const float* Whh_d = (const float*)d_in[6];
  const float* bih_d = (const float*)d_in[7];
  const float* bhh_d = (const float*)d_in[8];
  const float* Wd    = (const float*)d_in[9];
  const float* bd    = (const float*)d_in[10];
  float* out = (float*)d_out;

  float* Wc = (float*)d_ws;          // 512*128 floats
  float* bc = Wc + (size_t)Gn * Ln;  // 512 floats

  combine_dec_kernel<<<Gn, Ln, 0, stream>>>(Wih_d, Whh_d, bih_d, bhh_d, Wd, bd, Wc, bc);
  rae_persistent_kernel<<<Bn / 2, Gn, 0, stream>>>(x, Wih_e, Whh_e, bih_e, bhh_e,
                                                   Wc, bc, Wd, bd, out);
}

// Round 2
// 3988.143 us; speedup vs baseline: 13.2209x; 13.2209x over previous
//
#include <hip/hip_runtime.h>

// Problem constants (B,S,F,L) = (512, 1024, 64, 128)
constexpr int Bn = 512;
constexpr int Sn = 1024;
constexpr int Fn = 64;
constexpr int Ln = 128;
constexpr int Gn = 4 * Ln;  // 512 gate rows (i,f,g,o)

// ---- helpers ----
template <int CTRL>
__device__ __forceinline__ float dpp_add(float v) {
  int s = __builtin_amdgcn_mov_dpp(__float_as_int(v), CTRL, 0xF, 0xF, true);
  return v + __int_as_float(s);
}
// DPP ctrl: 0xB1 = quad_perm(1,0,3,2) = xor1; 0x4E = quad_perm(2,3,0,1) = xor2;
//           0x124 = row_ror:4; 0x128 = row_ror:8 (16-lane row reduce)

__device__ __forceinline__ float act_sig_tanh(float v, bool istanh) {
  // sigmoid(x) = rcp(1+exp(-x));  tanh(x) = 2*sigmoid(2x)-1  (shared path)
  float xx = istanh ? -2.0f * v : -v;
  float e = __expf(xx);
  float r = __builtin_amdgcn_rcpf(1.0f + e);
  return istanh ? 2.0f * r - 1.0f : r;
}
__device__ __forceinline__ float ftanh(float v) {
  float e = __expf(-2.0f * v);
  return 2.0f * __builtin_amdgcn_rcpf(1.0f + e) - 1.0f;
}

// Fold decoder dense layer into the decoder recurrence:
//   W_comb[t,l] = W_hh_dec[t,l] + sum_j W_ih_dec[t,j] * W_dense[j,l]
//   b_comb[t]   = b_ih_dec[t] + b_hh_dec[t] + sum_j W_ih_dec[t,j] * b_dense[j]
__global__ void combine_dec_kernel(const float* __restrict__ Wih, const float* __restrict__ Whh,
                                   const float* __restrict__ bih, const float* __restrict__ bhh,
                                   const float* __restrict__ Wd, const float* __restrict__ bd,
                                   float* __restrict__ Wc, float* __restrict__ bc) {
  const int t = blockIdx.x;   // gate row 0..511
  const int l = threadIdx.x;  // latent col 0..127
  float s = Whh[t * Ln + l];
#pragma unroll
  for (int j = 0; j < Fn; ++j) s += Wih[t * Fn + j] * Wd[j * Ln + l];
  Wc[t * Ln + l] = s;
  if (l == 0) {
    float sb = bih[t] + bhh[t];
#pragma unroll
    for (int j = 0; j < Fn; ++j) sb += Wih[t * Fn + j] * bd[j];
    bc[t] = sb;
  }
}

// Persistent RNN: 256 blocks x 1024 threads, 2 batch elems per block.
// Thread t: q = t&3 (K-quarter), rA = t>>2 (rows rA and rA+256).
// Weights 2x(32 h + 16 x) = 96 fp32 regs/thread -> fits the 128-VGPR cap at
// 16 waves/CU (the round-1 kernel needed ~230 and spilled 134 GB to scratch).
// Quarter partials all-reduced via DPP quad_perm (VALU, no LDS).
__global__ __launch_bounds__(1024, 4) void rae_persistent_kernel(
    const float* __restrict__ x,
    const float* __restrict__ Wih_e, const float* __restrict__ Whh_e,
    const float* __restrict__ bih_e, const float* __restrict__ bhh_e,
    const float* __restrict__ Wc, const float* __restrict__ bc,
    const float* __restrict__ Wd, const float* __restrict__ bd,
    float* __restrict__ out) {
  const int t = threadIdx.x;
  const int q = t & 3;    // K-quarter
  const int rA = t >> 2;  // row pair (rA, rA+256)
  const int b0 = blockIdx.x * 2;

  // Padded quarter layouts: quarter q at float offset q*68 (h) / q*36 (x) so the
  // 4 broadcast addresses per ds_read_b128 land on disjoint 4-bank groups.
  __shared__ __align__(16) float hs[4 * 68];  // h, elem-interleaved pairs, 34 float2/quarter (32 used + 2 pad)
  __shared__ __align__(16) float xq[4 * 36];  // x_t, elem-interleaved, 18 float2/quarter (16 used + 2 pad)
  __shared__ float gs[2 * Gn];                // activated gates: gs[row*2 + e]

  // ---- encoder weights into registers ----
  float wh[2][32];  // Whh_e[row, q*32 .. q*32+31]; reused for W_comb in decoder
  float wx[2][16];  // Wih_e[row, q*16 .. q*16+15]
#pragma unroll
  for (int rr = 0; rr < 2; ++rr) {
    const int row = rA + rr * 256;
    const float4* p = (const float4*)(Whh_e + row * Ln + q * 32);
#pragma unroll
    for (int k = 0; k < 8; ++k) {
      float4 v = p[k];
      wh[rr][4 * k] = v.x; wh[rr][4 * k + 1] = v.y; wh[rr][4 * k + 2] = v.z; wh[rr][4 * k + 3] = v.w;
    }
    const float4* px = (const float4*)(Wih_e + row * Fn + q * 16);
#pragma unroll
    for (int k = 0; k < 4; ++k) {
      float4 v = px[k];
      wx[rr][4 * k] = v.x; wx[rr][4 * k + 1] = v.y; wx[rr][4 * k + 2] = v.z; wx[rr][4 * k + 3] = v.w;
    }
  }
  float biasA = (q == 0) ? (bih_e[rA] + bhh_e[rA]) : 0.0f;
  float biasB = (q == 0) ? (bih_e[rA + 256] + bhh_e[rA + 256]) : 0.0f;

  // gate write slot: lane q writes (row, elem) = q==0:(rA,0) 1:(rA,1) 2:(rB,0) 3:(rB,1)
  const int g_row = (q < 2) ? rA : rA + 256;
  const int gofs = g_row * 2 + (q & 1);
  const bool istanh = (q >= 2) && (rA < 128);  // rows 256..383 are the g-gate (tanh)

  // cell-state ownership: t<256 holds c for (l = t&127, e = t>>7)
  const int cl = t & 127, ce = t >> 7;
  float c = 0.0f;

  const float* xp0 = x + (size_t)b0 * Sn * Fn;
  const float* xp1 = xp0 + (size_t)Sn * Fn;

  // init h = 0, prefetch x_0
  if (t < Ln) { hs[(t >> 5) * 68 + (t & 31) * 2] = 0.0f; hs[(t >> 5) * 68 + (t & 31) * 2 + 1] = 0.0f; }
  if (t >= 256 && t < 320) { int j = t - 256; xq[(j >> 4) * 36 + (j & 15) * 2] = xp0[j]; }
  else if (t >= 320 && t < 384) { int j = t - 320; xq[(j >> 4) * 36 + (j & 15) * 2 + 1] = xp1[j]; }
  __syncthreads();

  const float4* h4 = (const float4*)(hs + q * 68);  // this thread's h quarter (16 float4)
  const float4* x4 = (const float4*)(xq + q * 36);  // this thread's x quarter (8 float4)

  // ================= encoder: 1024 steps =================
  for (int step = 0; step < Sn; ++step) {
    float aA0 = biasA, aA1 = biasA, aB0 = biasB, aB1 = biasB;
#pragma unroll
    for (int k = 0; k < 8; ++k) {  // x part: features q*16+2k, +2k+1, both elems
      float4 v = x4[k];
      aA0 += wx[0][2 * k] * v.x + wx[0][2 * k + 1] * v.z;
      aA1 += wx[0][2 * k] * v.y + wx[0][2 * k + 1] * v.w;
      aB0 += wx[1][2 * k] * v.x + wx[1][2 * k + 1] * v.z;
      aB1 += wx[1][2 * k] * v.y + wx[1][2 * k + 1] * v.w;
    }
#pragma unroll
    for (int k = 0; k < 16; ++k) {  // h part: latents q*32+2k, +2k+1, both elems
      float4 v = h4[k];
      aA0 += wh[0][2 * k] * v.x + wh[0][2 * k + 1] * v.z;
      aA1 += wh[0][2 * k] * v.y + wh[0][2 * k + 1] * v.w;
      aB0 += wh[1][2 * k] * v.x + wh[1][2 * k + 1] * v.z;
      aB1 += wh[1][2 * k] * v.y + wh[1][2 * k + 1] * v.w;
    }
    // all-reduce across the 4 quarter-lanes (DPP xor1, xor2)
    aA0 = dpp_add<0xB1>(aA0); aA0 = dpp_add<0x4E>(aA0);
    aA1 = dpp_add<0xB1>(aA1); aA1 = dpp_add<0x4E>(aA1);
    aB0 = dpp_add<0xB1>(aB0); aB0 = dpp_add<0x4E>(aB0);
    aB1 = dpp_add<0xB1>(aB1); aB1 = dpp_add<0x4E>(aB1);
    float sel = (q == 0) ? aA0 : (q == 1) ? aA1 : (q == 2) ? aB0 : aB1;
    gs[gofs] = act_sig_tanh(sel, istanh);
    __syncthreads();
    if (t < 256) {  // waves 0-3: cell update (one (latent, elem) each)
      float gi = gs[cl * 2 + ce];
      float gf = gs[(Ln + cl) * 2 + ce];
      float gg = gs[(2 * Ln + cl) * 2 + ce];
      float go = gs[(3 * Ln + cl) * 2 + ce];
      c = gf * c + gi * gg;
      hs[(cl >> 5) * 68 + (cl & 31) * 2 + ce] = go * ftanh(c);
    } else if (t < 320) {  // wave 4: prefetch next x, elem 0
      if (step + 1 < Sn) { int j = t - 256; xq[(j >> 4) * 36 + (j & 15) * 2] = xp0[(step + 1) * Fn + j]; }
    } else if (t < 384) {  // wave 5: prefetch next x, elem 1
      if (step + 1 < Sn) { int j = t - 320; xq[(j >> 4) * 36 + (j & 15) * 2 + 1] = xp1[(step + 1) * Fn + j]; }
    }
    __syncthreads();
  }

  // ================= decoder: 1024 steps =================
#pragma unroll
  for (int rr = 0; rr < 2; ++rr) {  // reload wh with folded W_comb
    const float4* p = (const float4*)(Wc + (rA + rr * 256) * Ln + q * 32);
#pragma unroll
    for (int k = 0; k < 8; ++k) {
      float4 v = p[k];
      wh[rr][4 * k] = v.x; wh[rr][4 * k + 1] = v.y; wh[rr][4 * k + 2] = v.z; wh[rr][4 * k + 3] = v.w;
    }
  }
  biasA = (q == 0) ? bc[rA] : 0.0f;
  biasB = (q == 0) ? bc[rA + 256] : 0.0f;

  // dense epilogue: output oj = t>>4, 16 lanes cover 8 latents each
  const int oj = t >> 4, sl = t & 15;
  float dw[8];
  {
    const float4* p = (const float4*)(Wd + oj * Ln + sl * 8);
    float4 v0 = p[0], v1 = p[1];
    dw[0] = v0.x; dw[1] = v0.y; dw[2] = v0.z; dw[3] = v0.w;
    dw[4] = v1.x; dw[5] = v1.y; dw[6] = v1.z; dw[7] = v1.w;
  }
  const float dbias = bd[oj];
  float* op0 = out + (size_t)b0 * Sn * Fn;
  float* op1 = op0 + (size_t)Sn * Fn;
  const float4* he4 = (const float4*)hs;
  const int hei = (sl >> 2) * 17 + (sl & 3) * 4;  // padded-quarter float4 index of latent sl*8

  for (int step = 0; step < Sn; ++step) {
    float aA0 = biasA, aA1 = biasA, aB0 = biasB, aB1 = biasB;
#pragma unroll
    for (int k = 0; k < 16; ++k) {
      float4 v = h4[k];
      aA0 += wh[0][2 * k] * v.x + wh[0][2 * k + 1] * v.z;
      aA1 += wh[0][2 * k] * v.y + wh[0][2 * k + 1] * v.w;
      aB0 += wh[1][2 * k] * v.x + wh[1][2 * k + 1] * v.z;
      aB1 += wh[1][2 * k] * v.y + wh[1][2 * k + 1] * v.w;
    }
    aA0 = dpp_add<0xB1>(aA0); aA0 = dpp_add<0x4E>(aA0);
    aA1 = dpp_add<0xB1>(aA1); aA1 = dpp_add<0x4E>(aA1);
    aB0 = dpp_add<0xB1>(aB0); aB0 = dpp_add<0x4E>(aB0);
    aB1 = dpp_add<0xB1>(aB1); aB1 = dpp_add<0x4E>(aB1);
    float sel = (q == 0) ? aA0 : (q == 1) ? aA1 : (q == 2) ? aB0 : aB1;
    gs[gofs] = act_sig_tanh(sel, istanh);
    __syncthreads();
    if (t < 256) {
      float gi = gs[cl * 2 + ce];
      float gf = gs[(Ln + cl) * 2 + ce];
      float gg = gs[(2 * Ln + cl) * 2 + ce];
      float go = gs[(3 * Ln + cl) * 2 + ce];
      c = gf * c + gi * gg;
      hs[(cl >> 5) * 68 + (cl & 31) * 2 + ce] = go * ftanh(c);
    }
    __syncthreads();
    // dense epilogue: out[b, S-1-step, :] = W_dense @ h + b_dense
    float d0 = 0.0f, d1 = 0.0f;
#pragma unroll
    for (int k = 0; k < 4; ++k) {
      float4 v = he4[hei + k];
      d0 += dw[2 * k] * v.x + dw[2 * k + 1] * v.z;
      d1 += dw[2 * k] * v.y + dw[2 * k + 1] * v.w;
    }
    d0 = dpp_add<0xB1>(d0); d0 = dpp_add<0x4E>(d0); d0 = dpp_add<0x124>(d0); d0 = dpp_add<0x128>(d0);
    d1 = dpp_add<0xB1>(d1); d1 = dpp_add<0x4E>(d1); d1 = dpp_add<0x124>(d1); d1 = dpp_add<0x128>(d1);
    if (sl == 0) {
      const int row = Sn - 1 - step;
      op0[(size_t)row * Fn + oj] = d0 + dbias;
      op1[(size_t)row * Fn + oj] = d1 + dbias;
    }
  }
}

extern "C" void kernel_launch(void* const* d_in, const int* in_sizes, int n_in,
                              void* d_out, int out_size, void* d_ws, size_t ws_size,
                              hipStream_t stream) {
  const float* x     = (const float*)d_in[0];
  const float* Wih_e = (const float*)d_in[1];
  const float* Whh_e = (const float*)d_in[2];
  const float* bih_e = (const float*)d_in[3];
  const float* bhh_e = (const float*)d_in[4];
  const float* Wih_d = (const float*)d_in[5];
  const float* Whh_d = (const float*)d_in[6];
  const float* bih_d = (const float*)d_in[7];
  const float* bhh_d = (const float*)d_in[8];
  const float* Wd    = (const float*)d_in[9];
  const float* bd    = (const float*)d_in[10];
  float* out = (float*)d_out;

  float* Wc = (float*)d_ws;          // 512*128 floats
  float* bc = Wc + (size_t)Gn * Ln;  // 512 floats

  combine_dec_kernel<<<Gn, Ln, 0, stream>>>(Wih_d, Whh_d, bih_d, bhh_d, Wd, bd, Wc, bc);
  rae_persistent_kernel<<<Bn / 2, 1024, 0, stream>>>(x, Wih_e, Whh_e, bih_e, bhh_e,
                                                     Wc, bc, Wd, bd, out);
}